// Round 1
// baseline (657.749 us; speedup 1.0000x reference)
//
#include <hip/hip_runtime.h>
#include <hip/hip_bf16.h>

#define D_DIM   128
#define S_GRP   128
#define MARGINF 2.0f
#define KMARG   0.02f
#define EPSF    1e-6f

// ---------------------------------------------------------------------------
// Kernel 1: d[r] = 1 - dot(z_r[r], z_v[r]); fused label-masked sums for l_cdd.
// Half-wave (32 lanes) per row, float4 loads (16B/lane coalescing sweet spot).
// ---------------------------------------------------------------------------
__global__ __launch_bounds__(256) void compute_d_kernel(
    const float* __restrict__ zr, const float* __restrict__ zv,
    const int* __restrict__ labels, float* __restrict__ out,
    double* __restrict__ wsd, int* __restrict__ wsi, int n)
{
    const int tid    = blockIdx.x * blockDim.x + threadIdx.x;
    const int wave   = tid >> 6;
    const int lane   = threadIdx.x & 63;
    const int nwaves = (gridDim.x * blockDim.x) >> 6;
    const int half   = lane >> 5;   // which row of the pair
    const int sub    = lane & 31;   // float4 slot within row (32*16B = 512B)
    const int npairs = n >> 1;

    float accB = 0.f, accP = 0.f;
    int   cntB = 0,   cntP = 0;

    for (int pi = wave; pi < npairs; pi += nwaves) {
        const int r = 2 * pi + half;
        const float4* a = (const float4*)(zr + (size_t)r * D_DIM);
        const float4* b = (const float4*)(zv + (size_t)r * D_DIM);
        float4 x = a[sub];
        float4 y = b[sub];
        float p = x.x * y.x + x.y * y.y + x.z * y.z + x.w * y.w;
        // reduce within each 32-lane half
        #pragma unroll
        for (int off = 16; off; off >>= 1) p += __shfl_xor(p, off);
        if (sub == 0) {
            float dv = 1.0f - p;
            out[2 + r] = dv;
            if (labels[r] == 0) { accB += dv; cntB++; }
            else                { accP += dv; cntP++; }
        }
    }
    // combine the two half-wave leaders (lanes 0 and 32)
    accB += __shfl_xor(accB, 32);
    accP += __shfl_xor(accP, 32);
    cntB += __shfl_xor(cntB, 32);
    cntP += __shfl_xor(cntP, 32);

    __shared__ float sB[4], sP[4];
    __shared__ int   iB[4], iP[4];
    const int w = threadIdx.x >> 6;
    if (lane == 0) { sB[w] = accB; sP[w] = accP; iB[w] = cntB; iP[w] = cntP; }
    __syncthreads();
    if (threadIdx.x == 0) {
        float tb = 0.f, tp = 0.f; int cb = 0, cp = 0;
        #pragma unroll
        for (int i = 0; i < 4; ++i) { tb += sB[i]; tp += sP[i]; cb += iB[i]; cp += iP[i]; }
        atomicAdd(&wsd[0], (double)tb);
        atomicAdd(&wsd[1], (double)tp);
        atomicAdd(&wsi[0], cb);
        atomicAdd(&wsi[1], cp);
    }
}

// ---------------------------------------------------------------------------
// 128-thread (2-wave) block sum reduction, result broadcast to all threads.
// ---------------------------------------------------------------------------
__device__ __forceinline__ float block_reduce_128(float x, volatile float* sh)
{
    #pragma unroll
    for (int off = 32; off; off >>= 1) x += __shfl_xor(x, off);
    __syncthreads();                       // protect sh from previous use
    if ((threadIdx.x & 63) == 0) sh[threadIdx.x >> 6] = x;
    __syncthreads();
    return sh[0] + sh[1];
}

// ---------------------------------------------------------------------------
// Kernel 2: per-group corr + neighbor + pairwise rank losses. 1 block / group.
// Stable O(S^2) rank-count sort matches jnp.argsort's stable tie-breaking
// (neigh_viol is tie-order-sensitive; rank_loss is permutation-invariant).
// ---------------------------------------------------------------------------
__global__ __launch_bounds__(128) void group_kernel(
    const int* __restrict__ var_lens, const float* __restrict__ dvals,
    double* __restrict__ pcc_sum)
{
    const int g = blockIdx.x;
    const int t = threadIdx.x;
    __shared__ float sv[S_GRP], sd[S_GRP], svs[S_GRP], sds[S_GRP];
    __shared__ float sred[2];

    const float v = (float)var_lens[(size_t)g * S_GRP + t];
    const float d = dvals[(size_t)g * S_GRP + t];
    sv[t] = v; sd[t] = d;

    // means (first reduce's internal sync also publishes sv/sd)
    const float mv = block_reduce_128(v, sred) * (1.0f / S_GRP);
    const float md = block_reduce_128(d, sred) * (1.0f / S_GRP);
    const float cv = v - mv, cd = d - md;

    // ddof=1 stds
    const float ssv = block_reduce_128(cv * cv, sred);
    const float ssd = block_reduce_128(cd * cd, sred);
    const float vs  = sqrtf(ssv * (1.0f / (S_GRP - 1)));
    const float dsd = sqrtf(ssd * (1.0f / (S_GRP - 1)));

    // corr loss
    const float vz = cv / (vs + EPSF);
    const float dz = cd / (dsd + EPSF);
    const float df = vz - dz;
    float corr = block_reduce_128(df * df, sred) * (1.0f / S_GRP);
    if (!(vs > 0.f && dsd > 0.f)) corr = 0.f;

    // stable rank via counting (LDS broadcast reads: all lanes same j)
    int rank = 0;
    #pragma unroll 8
    for (int j = 0; j < S_GRP; ++j) {
        const float vj = sv[j];
        rank += (vj < v) || (vj == v && j < t);
    }
    svs[rank] = v; sds[rank] = d;
    __syncthreads();

    // neighbor violation: mean over S-1 adjacent sorted pairs
    float nv = 0.f;
    if (t < S_GRP - 1) nv = fmaxf(sds[t] - sds[t + 1] + KMARG, 0.f);
    const float neigh = block_reduce_128(nv, sred) * (1.0f / (S_GRP - 1));

    // pairwise rank loss over pairs with v[j] > v[i]
    const float myv = svs[t], myd = sds[t];
    float viol = 0.f, cnt = 0.f;
    #pragma unroll 8
    for (int j = 0; j < S_GRP; ++j) {
        const float vj = svs[j];
        if (vj > myv) {
            cnt  += 1.f;
            viol += fmaxf(KMARG - (sds[j] - myd), 0.f);
        }
    }
    const float violT = block_reduce_128(viol, sred);
    const float cntT  = block_reduce_128(cnt,  sred);
    const float rloss = (cntT > 0.f) ? violT / cntT : 0.f;

    if (t == 0) atomicAdd(pcc_sum, (double)(corr + neigh + rloss));
}

// ---------------------------------------------------------------------------
// Kernel 3: scalar finalize.
// ---------------------------------------------------------------------------
__global__ void finalize_kernel(const double* __restrict__ wsd,
                                const int* __restrict__ wsi,
                                float* __restrict__ out, int nGroups)
{
    if (threadIdx.x == 0 && blockIdx.x == 0) {
        const int nb = wsi[0], np_ = wsi[1];
        const double mean_b = wsd[0] / (double)(nb  > 0 ? nb  : 1);
        const double mean_p = wsd[1] / (double)(np_ > 0 ? np_ : 1);
        float l = 0.f;
        if (nb > 0 && np_ > 0) {
            const double v = (double)MARGINF + mean_b - mean_p;
            l = (float)(v > 0.0 ? v : 0.0);
        }
        out[0] = l;
        out[1] = (float)(wsd[2] / (double)nGroups);
    }
}

extern "C" void kernel_launch(void* const* d_in, const int* in_sizes, int n_in,
                              void* d_out, int out_size, void* d_ws, size_t ws_size,
                              hipStream_t stream)
{
    const float* zr       = (const float*)d_in[0];
    const float* zv       = (const float*)d_in[1];
    const int*   labels   = (const int*)d_in[2];
    // d_in[3] = groups (arange//S, implied by contiguous layout) — unused
    const int*   var_lens = (const int*)d_in[4];
    float* out = (float*)d_out;

    const int N = in_sizes[2];      // labels length = N
    const int G = N / S_GRP;

    double* wsd = (double*)d_ws;                         // [sum_b, sum_p, pcc_sum]
    int*    wsi = (int*)((char*)d_ws + 3 * sizeof(double)); // [cnt_b, cnt_p]

    // ws is re-poisoned to 0xAA before every launch — zero accumulators.
    hipMemsetAsync(d_ws, 0, 3 * sizeof(double) + 2 * sizeof(int), stream);

    compute_d_kernel<<<2048, 256, 0, stream>>>(zr, zv, labels, out, wsd, wsi, N);
    group_kernel<<<G, 128, 0, stream>>>(var_lens, out + 2, wsd + 2);
    finalize_kernel<<<1, 64, 0, stream>>>(wsd, wsi, out, G);
}

// Round 4
// 555.685 us; speedup vs baseline: 1.1837x; 1.1837x over previous
//
#include <hip/hip_runtime.h>
#include <hip/hip_bf16.h>

#define D_DIM   128
#define S_GRP   128
#define MARGINF 2.0f
#define KMARG   0.02f
#define EPSF    1e-6f

#define CD_BLOCKS  1024
#define CD_THREADS 256
#define U_PAIRS    8     // pairs per wave-iteration: 16 float4 loads in flight

// ---------------------------------------------------------------------------
// compute_d core: d[r] = 1 - dot(z_r[r], z_v[r]) + label-masked sums.
// Half-wave (32 lanes) per row; U_PAIRS batched per iteration so 16 global
// float4 loads are outstanding before any reduction (R1 was issue-limited:
// VALUBusy 4.9%, hbm 15%, only 2 loads/wave in flight).
// Template flag selects partials-to-ws vs 32-byte atomic fallback.
// ---------------------------------------------------------------------------
template <bool USE_PARTIALS>
__global__ __launch_bounds__(CD_THREADS) void compute_d_kernel(
    const float* __restrict__ zr, const float* __restrict__ zv,
    const int* __restrict__ labels, float* __restrict__ dout,
    float* __restrict__ partB, float* __restrict__ partP,
    int* __restrict__ pcntB, int* __restrict__ pcntP,
    double* __restrict__ wsd, int* __restrict__ wsi, int npairs)
{
    const int tid    = blockIdx.x * blockDim.x + threadIdx.x;
    const int wave   = tid >> 6;
    const int lane   = threadIdx.x & 63;
    const int nwaves = (gridDim.x * blockDim.x) >> 6;
    const int half   = lane >> 5;   // which row of the pair
    const int sub    = lane & 31;   // float4 slot within row

    float accB = 0.f, accP = 0.f;
    int   cntB = 0,   cntP = 0;

    const int nchunks = npairs / U_PAIRS;   // exact: 262144 / 8

    for (int c = wave; c < nchunks; c += nwaves) {
        const int pair0 = c * U_PAIRS;
        float4 x[U_PAIRS], y[U_PAIRS];
        #pragma unroll
        for (int u = 0; u < U_PAIRS; ++u) {
            const size_t r = (size_t)(2 * (pair0 + u) + half);
            x[u] = ((const float4*)(zr + r * D_DIM))[sub];
            y[u] = ((const float4*)(zv + r * D_DIM))[sub];
        }
        float p[U_PAIRS];
        #pragma unroll
        for (int u = 0; u < U_PAIRS; ++u)
            p[u] = x[u].x * y[u].x + x[u].y * y[u].y
                 + x[u].z * y[u].z + x[u].w * y[u].w;
        // 8 independent 5-step chains — pipelined on the DS pipe
        #pragma unroll
        for (int off = 16; off; off >>= 1) {
            #pragma unroll
            for (int u = 0; u < U_PAIRS; ++u) p[u] += __shfl_xor(p[u], off);
        }
        if (sub == 0) {
            #pragma unroll
            for (int u = 0; u < U_PAIRS; ++u) {
                const int r = 2 * (pair0 + u) + half;
                const float dv = 1.0f - p[u];
                dout[r] = dv;
                if (labels[r] == 0) { accB += dv; cntB++; }
                else                { accP += dv; cntP++; }
            }
        }
    }

    // non-leader lanes hold zeros, so a full xor-reduce is correct
    #pragma unroll
    for (int off = 32; off; off >>= 1) {
        accB += __shfl_xor(accB, off);
        accP += __shfl_xor(accP, off);
        cntB += __shfl_xor(cntB, off);
        cntP += __shfl_xor(cntP, off);
    }
    __shared__ float sB[4], sP[4];
    __shared__ int   iB[4], iP[4];
    const int w = threadIdx.x >> 6;
    if (lane == 0) { sB[w] = accB; sP[w] = accP; iB[w] = cntB; iP[w] = cntP; }
    __syncthreads();
    if (threadIdx.x == 0) {
        const float tB = sB[0] + sB[1] + sB[2] + sB[3];
        const float tP = sP[0] + sP[1] + sP[2] + sP[3];
        const int   cB = iB[0] + iB[1] + iB[2] + iB[3];
        const int   cP = iP[0] + iP[1] + iP[2] + iP[3];
        if (USE_PARTIALS) {
            partB[blockIdx.x] = tB;
            partP[blockIdx.x] = tP;
            pcntB[blockIdx.x] = cB;
            pcntP[blockIdx.x] = cP;
        } else {
            atomicAdd(&wsd[0], (double)tB);
            atomicAdd(&wsd[1], (double)tP);
            atomicAdd(&wsi[0], cB);
            atomicAdd(&wsi[1], cP);
        }
    }
}

// ---------------------------------------------------------------------------
// 128-thread (2-wave) block sum reduction, result broadcast to all threads.
// ---------------------------------------------------------------------------
__device__ __forceinline__ float block_reduce_128(float x, volatile float* sh)
{
    #pragma unroll
    for (int off = 32; off; off >>= 1) x += __shfl_xor(x, off);
    __syncthreads();                       // protect sh from previous use
    if ((threadIdx.x & 63) == 0) sh[threadIdx.x >> 6] = x;
    __syncthreads();
    return sh[0] + sh[1];
}

// ---------------------------------------------------------------------------
// Per-group corr + neighbor + pairwise rank losses. 1 block/group.
// Stable O(S^2) rank-count sort matches jnp.argsort's stable tie-breaking.
// ---------------------------------------------------------------------------
template <bool USE_PARTIALS>
__global__ __launch_bounds__(128) void group_kernel(
    const int* __restrict__ var_lens, const float* __restrict__ dvals,
    float* __restrict__ gl, double* __restrict__ pcc_sum)
{
    const int g = blockIdx.x;
    const int t = threadIdx.x;
    __shared__ float sv[S_GRP], sd[S_GRP], svs[S_GRP], sds[S_GRP];
    __shared__ float sred[2];

    const float v = (float)var_lens[(size_t)g * S_GRP + t];
    const float d = dvals[(size_t)g * S_GRP + t];
    sv[t] = v; sd[t] = d;

    const float mv = block_reduce_128(v, sred) * (1.0f / S_GRP);
    const float md = block_reduce_128(d, sred) * (1.0f / S_GRP);
    const float cv = v - mv, cd = d - md;

    const float ssv = block_reduce_128(cv * cv, sred);
    const float ssd = block_reduce_128(cd * cd, sred);
    const float vs  = sqrtf(ssv * (1.0f / (S_GRP - 1)));
    const float dsd = sqrtf(ssd * (1.0f / (S_GRP - 1)));

    const float vz = cv / (vs + EPSF);
    const float dz = cd / (dsd + EPSF);
    const float df = vz - dz;
    float corr = block_reduce_128(df * df, sred) * (1.0f / S_GRP);
    if (!(vs > 0.f && dsd > 0.f)) corr = 0.f;

    // stable rank via counting (LDS broadcast reads — conflict-free)
    int rank = 0;
    #pragma unroll 8
    for (int j = 0; j < S_GRP; ++j) {
        const float vj = sv[j];
        rank += (vj < v) || (vj == v && j < t);
    }
    svs[rank] = v; sds[rank] = d;
    __syncthreads();

    float nv = 0.f;
    if (t < S_GRP - 1) nv = fmaxf(sds[t] - sds[t + 1] + KMARG, 0.f);
    const float neigh = block_reduce_128(nv, sred) * (1.0f / (S_GRP - 1));

    const float myv = svs[t], myd = sds[t];
    float viol = 0.f, cnt = 0.f;
    #pragma unroll 8
    for (int j = 0; j < S_GRP; ++j) {
        const float vj = svs[j];
        if (vj > myv) {
            cnt  += 1.f;
            viol += fmaxf(KMARG - (sds[j] - myd), 0.f);
        }
    }
    const float violT = block_reduce_128(viol, sred);
    const float cntT  = block_reduce_128(cnt,  sred);
    const float rloss = (cntT > 0.f) ? violT / cntT : 0.f;

    if (t == 0) {
        const float total = corr + neigh + rloss;
        if (USE_PARTIALS) gl[g] = total;
        else              atomicAdd(pcc_sum, (double)total);
    }
}

// ---------------------------------------------------------------------------
// Finalize (partials path): reduce per-block/per-group partials in one block.
// ---------------------------------------------------------------------------
__global__ __launch_bounds__(256) void finalize_kernel(
    const float* __restrict__ partB, const float* __restrict__ partP,
    const int* __restrict__ pcntB, const int* __restrict__ pcntP,
    const float* __restrict__ gl, float* __restrict__ out,
    int nPart, int nGroups)
{
    double a0 = 0.0, a1 = 0.0, a2 = 0.0, a3 = 0.0, a4 = 0.0;
    for (int i = threadIdx.x; i < nPart; i += 256) {
        a0 += (double)partB[i];
        a1 += (double)partP[i];
        a2 += (double)pcntB[i];
        a3 += (double)pcntP[i];
    }
    for (int i = threadIdx.x; i < nGroups; i += 256)
        a4 += (double)gl[i];

    #pragma unroll
    for (int off = 32; off; off >>= 1) {
        a0 += __shfl_xor(a0, off);
        a1 += __shfl_xor(a1, off);
        a2 += __shfl_xor(a2, off);
        a3 += __shfl_xor(a3, off);
        a4 += __shfl_xor(a4, off);
    }
    __shared__ double red[5][4];
    const int w = threadIdx.x >> 6;
    if ((threadIdx.x & 63) == 0) {
        red[0][w] = a0; red[1][w] = a1; red[2][w] = a2; red[3][w] = a3; red[4][w] = a4;
    }
    __syncthreads();
    if (threadIdx.x == 0) {
        const double sB = red[0][0] + red[0][1] + red[0][2] + red[0][3];
        const double sP = red[1][0] + red[1][1] + red[1][2] + red[1][3];
        const double cB = red[2][0] + red[2][1] + red[2][2] + red[2][3];
        const double cP = red[3][0] + red[3][1] + red[3][2] + red[3][3];
        const double sG = red[4][0] + red[4][1] + red[4][2] + red[4][3];
        const double mean_b = sB / (cB > 0.0 ? cB : 1.0);
        const double mean_p = sP / (cP > 0.0 ? cP : 1.0);
        float l = 0.f;
        if (cB > 0.0 && cP > 0.0) {
            const double vv = (double)MARGINF + mean_b - mean_p;
            l = (float)(vv > 0.0 ? vv : 0.0);
        }
        out[0] = l;
        out[1] = (float)(sG / (double)nGroups);
    }
}

// ---------------------------------------------------------------------------
// Finalize (atomic fallback path): read 32-byte accumulator block.
// ---------------------------------------------------------------------------
__global__ void finalize_atomic_kernel(const double* __restrict__ wsd,
                                       const int* __restrict__ wsi,
                                       float* __restrict__ out, int nGroups)
{
    if (threadIdx.x == 0 && blockIdx.x == 0) {
        const int nb = wsi[0], np_ = wsi[1];
        const double mean_b = wsd[0] / (double)(nb  > 0 ? nb  : 1);
        const double mean_p = wsd[1] / (double)(np_ > 0 ? np_ : 1);
        float l = 0.f;
        if (nb > 0 && np_ > 0) {
            const double v = (double)MARGINF + mean_b - mean_p;
            l = (float)(v > 0.0 ? v : 0.0);
        }
        out[0] = l;
        out[1] = (float)(wsd[2] / (double)nGroups);
    }
}

extern "C" void kernel_launch(void* const* d_in, const int* in_sizes, int n_in,
                              void* d_out, int out_size, void* d_ws, size_t ws_size,
                              hipStream_t stream)
{
    const float* zr       = (const float*)d_in[0];
    const float* zv       = (const float*)d_in[1];
    const int*   labels   = (const int*)d_in[2];
    // d_in[3] = groups (arange//S, implied by contiguous layout) — unused
    const int*   var_lens = (const int*)d_in[4];
    float* out = (float*)d_out;

    const int N = in_sizes[2];      // labels length = N
    const int G = N / S_GRP;

    const size_t need = (size_t)CD_BLOCKS * 16 + (size_t)G * 4;

    if (ws_size >= need) {
        // partials path — no global atomics, no memset
        float* partB = (float*)d_ws;                        // [CD_BLOCKS]
        float* partP = partB + CD_BLOCKS;                   // [CD_BLOCKS]
        int*   pcntB = (int*)(partP + CD_BLOCKS);           // [CD_BLOCKS]
        int*   pcntP = pcntB + CD_BLOCKS;                   // [CD_BLOCKS]
        float* gl    = (float*)(pcntP + CD_BLOCKS);         // [G]

        compute_d_kernel<true><<<CD_BLOCKS, CD_THREADS, 0, stream>>>(
            zr, zv, labels, out + 2, partB, partP, pcntB, pcntP,
            nullptr, nullptr, N / 2);
        group_kernel<true><<<G, 128, 0, stream>>>(var_lens, out + 2, gl, nullptr);
        finalize_kernel<<<1, 256, 0, stream>>>(partB, partP, pcntB, pcntP, gl,
                                               out, CD_BLOCKS, G);
    } else {
        // 32-byte atomic fallback (R1-proven footprint)
        double* wsd = (double*)d_ws;                           // [3]
        int*    wsi = (int*)((char*)d_ws + 3 * sizeof(double)); // [2]
        hipMemsetAsync(d_ws, 0, 3 * sizeof(double) + 2 * sizeof(int), stream);

        compute_d_kernel<false><<<CD_BLOCKS, CD_THREADS, 0, stream>>>(
            zr, zv, labels, out + 2, nullptr, nullptr, nullptr, nullptr,
            wsd, wsi, N / 2);
        group_kernel<false><<<G, 128, 0, stream>>>(var_lens, out + 2, nullptr,
                                                   wsd + 2);
        finalize_atomic_kernel<<<1, 64, 0, stream>>>(wsd, wsi, out, G);
    }
}